// Round 2
// baseline (266.757 us; speedup 1.0000x reference)
//
#include <hip/hip_runtime.h>
#include <hip/hip_bf16.h>
#include <stdint.h>

#define NPTS   131072
#define NANCH  1024
#define GRID   25
#define NCELL  (GRID*GRID)
#define CINV   0.25f
#define MAXP   512
#define MINP   4

// ---------------- binning kernels ----------------

__global__ void k_zero(int* __restrict__ hist, int* __restrict__ fill) {
    int t = threadIdx.x;
    if (t < NCELL) { hist[t] = 0; fill[t] = 0; }
}

__global__ void k_hist(const float* __restrict__ pts, int* __restrict__ cellid,
                       int* __restrict__ hist) {
    int i = blockIdx.x * blockDim.x + threadIdx.x;
    if (i >= NPTS) return;
    float px = pts[3*i], py = pts[3*i+1];
    int cx = (int)(px * CINV); cx = cx < 0 ? 0 : (cx > GRID-1 ? GRID-1 : cx);
    int cy = (int)(py * CINV); cy = cy < 0 ? 0 : (cy > GRID-1 ? GRID-1 : cy);
    int c = cy * GRID + cx;
    cellid[i] = c;
    atomicAdd(&hist[c], 1);
}

__global__ void k_scan(const int* __restrict__ hist, int* __restrict__ cstart) {
    __shared__ int sc[1024];
    int t = threadIdx.x;
    int v = (t < NCELL) ? hist[t] : 0;
    sc[t] = v;
    __syncthreads();
    for (int off = 1; off < 1024; off <<= 1) {
        int x = (t >= off) ? sc[t - off] : 0;
        __syncthreads();
        sc[t] += x;
        __syncthreads();
    }
    if (t < NCELL) cstart[t] = sc[t] - v;       // exclusive
    if (t == NCELL-1) cstart[NCELL] = sc[t];    // total
}

__global__ void k_scatter(const float* __restrict__ pts, const int* __restrict__ cellid,
                          const int* __restrict__ cstart, int* __restrict__ fill,
                          float* __restrict__ bx, float* __restrict__ by,
                          float* __restrict__ bz) {
    int i = blockIdx.x * blockDim.x + threadIdx.x;
    if (i >= NPTS) return;
    int c = cellid[i];
    int pos = cstart[c] + atomicAdd(&fill[c], 1);
    bx[pos] = pts[3*i]; by[pos] = pts[3*i+1]; bz[pos] = pts[3*i+2];
}

// ---------------- main kernel: one block per anchor ----------------

__launch_bounds__(256)
__global__ void k_main(const float* __restrict__ pts,    // original order (fallback)
                       const float* __restrict__ anch,
                       const float* __restrict__ W1, const float* __restrict__ b1,
                       const float* __restrict__ W2, const float* __restrict__ b2,
                       const float* __restrict__ Wc, const float* __restrict__ bc,
                       const float* __restrict__ Wr, const float* __restrict__ br,
                       const float* __restrict__ bx, const float* __restrict__ by,
                       const float* __restrict__ bz, const int* __restrict__ cstart,
                       float* __restrict__ out) {
    __shared__ float spx[MAXP], spy[MAXP], spz[MAXP];  // gathered rel coords
    __shared__ float h1t[16][64];                      // h1 batch, [point][dim]
    __shared__ float w1s[3][64];
    __shared__ float b1s[64];
    __shared__ float gmax2[128];
    __shared__ int   s_cnt;
    __shared__ int   s_wcnt[4];

    const int a   = blockIdx.x;
    const int tid = threadIdx.x;
    const float ax = anch[6*a],   ay = anch[6*a+1];
    const float w  = anch[6*a+3], l  = anch[6*a+4], hh = anch[6*a+5];
    const float hw = w * 0.5f, hl = l * 0.5f;
    const float x0 = ax - hw, x1 = ax + hw, y0 = ay - hl, y1 = ay + hl;

    if (tid == 0) s_cnt = 0;
    if (tid < 64) {
        w1s[0][tid] = W1[tid]; w1s[1][tid] = W1[64+tid]; w1s[2][tid] = W1[128+tid];
        b1s[tid] = b1[tid];
    }
    // W2 column for this thread's output dim, register-resident
    const int d = tid & 127;
    float w2col[64];
    #pragma unroll
    for (int i = 0; i < 64; i++) w2col[i] = W2[i*128 + d];
    const float b2reg = b2[d];
    __syncthreads();

    // ---- phase A: gather inside points from overlapping cells (unordered) ----
    int cx0 = (int)floorf(x0 * CINV); if (cx0 < 0) cx0 = 0;
    int cx1 = (int)floorf(x1 * CINV); if (cx1 > GRID-1) cx1 = GRID-1;
    int cy0 = (int)floorf(y0 * CINV); if (cy0 < 0) cy0 = 0;
    int cy1 = (int)floorf(y1 * CINV); if (cy1 > GRID-1) cy1 = GRID-1;
    const int lane = tid & 63, wv = tid >> 6;

    for (int cy = cy0; cy <= cy1; cy++)
        for (int cx = cx0; cx <= cx1; cx++) {
            int c = cy * GRID + cx;
            int p0 = cstart[c], p1 = cstart[c+1];
            for (int base = p0; base < p1; base += 256) {
                int i = base + tid;
                if (i < p1) {
                    float px = bx[i], py = by[i], pz = bz[i];
                    bool ins = (px >= x0) & (px <= x1) & (py >= y0) & (py <= y1)
                             & (pz >= 0.f) & (pz <= hh);
                    if (ins) {
                        int pos = atomicAdd(&s_cnt, 1);
                        if (pos < MAXP) { spx[pos] = px - ax; spy[pos] = py - ay; spz[pos] = pz; }
                    }
                }
            }
        }
    __syncthreads();
    const int cnt = s_cnt;

    // ---- rare fallback: count>512 needs "first 512 by original index" ----
    if (cnt > MAXP) {
        __syncthreads();
        int basecnt = 0;
        for (int st = 0; st < NPTS && basecnt < MAXP; st += 256) {
            int i = st + tid;
            float px = pts[3*i], py = pts[3*i+1], pz = pts[3*i+2];
            bool ins = (px >= x0) & (px <= x1) & (py >= y0) & (py <= y1)
                     & (pz >= 0.f) & (pz <= hh);
            unsigned long long m = __ballot(ins);
            int pref = __popcll(m & ((1ull << lane) - 1ull));
            if (lane == 0) s_wcnt[wv] = __popcll(m);
            __syncthreads();
            int off = basecnt;
            for (int k = 0; k < wv; k++) off += s_wcnt[k];
            int tot = s_wcnt[0] + s_wcnt[1] + s_wcnt[2] + s_wcnt[3];
            if (ins) {
                int pos = off + pref;
                if (pos < MAXP) { spx[pos] = px - ax; spy[pos] = py - ay; spz[pos] = pz; }
            }
            basecnt += tot;
            __syncthreads();
        }
    }

    if (cnt < MINP) {               // zeroed row (valid==0)
        if (tid < 5) out[5*a + tid] = 0.f;
        return;
    }
    const int gathered = cnt < MAXP ? cnt : MAXP;

    // ---- phase B: MLP + max over points ----
    // threads: dim = tid&127 (w2col in regs), two point-streams (tid>>7)
    float gmax = 0.f;               // all h2 are relu'd >= 0
    const int sstream = tid >> 7;
    for (int pb = 0; pb < gathered; pb += 16) {
        int lim = gathered - pb; if (lim > 16) lim = 16;
        // h1 for up to 16 points: wave wv computes points 4*wv..4*wv+3, lane=dim j
        {
            const int j = tid & 63, pw = tid >> 6;
            #pragma unroll
            for (int k = 0; k < 4; k++) {
                int p = pw * 4 + k;
                if (p < lim) {
                    float qx = spx[pb+p], qy = spy[pb+p], qz = spz[pb+p];
                    float v = fmaf(qz, w1s[2][j],
                              fmaf(qy, w1s[1][j],
                              fmaf(qx, w1s[0][j], b1s[j])));
                    h1t[p][j] = fmaxf(v, 0.f);
                }
            }
        }
        __syncthreads();
        #pragma unroll
        for (int k = 0; k < 8; k++) {
            int p = sstream * 8 + k;
            if (p < lim) {
                const float4* hp = (const float4*)&h1t[p][0];  // broadcast reads
                float acc = b2reg;
                #pragma unroll
                for (int i4 = 0; i4 < 16; i4++) {
                    float4 hv = hp[i4];
                    acc = fmaf(hv.x, w2col[4*i4+0], acc);
                    acc = fmaf(hv.y, w2col[4*i4+1], acc);
                    acc = fmaf(hv.z, w2col[4*i4+2], acc);
                    acc = fmaf(hv.w, w2col[4*i4+3], acc);
                }
                gmax = fmaxf(gmax, acc);   // relu folded into running max (>=0)
            }
        }
        __syncthreads();
    }

    // combine the two point-streams
    if (sstream == 1) gmax2[d] = gmax;
    __syncthreads();
    if (sstream == 0) gmax2[d] = fmaxf(gmax2[d], gmax);
    __syncthreads();

    // final heads: out = [g@Wc+bc, g@Wr+br]
    if (tid < 5) {
        const float* Wv; float bias; int stride;
        if (tid == 0) { Wv = Wc;            bias = bc[0];      stride = 1; }
        else          { Wv = Wr + (tid-1);  bias = br[tid-1];  stride = 4; }
        float acc = bias;
        for (int i = 0; i < 128; i++) acc = fmaf(gmax2[i], Wv[i*stride], acc);
        out[5*a + tid] = acc;
    }
}

// ---------------- launch ----------------

extern "C" void kernel_launch(void* const* d_in, const int* in_sizes, int n_in,
                              void* d_out, int out_size, void* d_ws, size_t ws_size,
                              hipStream_t stream) {
    const float* pts  = (const float*)d_in[0];
    const float* anch = (const float*)d_in[1];
    const float* W1   = (const float*)d_in[2];
    const float* b1   = (const float*)d_in[3];
    const float* W2   = (const float*)d_in[4];
    const float* b2   = (const float*)d_in[5];
    const float* Wc   = (const float*)d_in[6];
    const float* bc   = (const float*)d_in[7];
    const float* Wr   = (const float*)d_in[8];
    const float* br   = (const float*)d_in[9];
    float* out = (float*)d_out;

    char* ws = (char*)d_ws;
    int*   hist   = (int*)ws;                       // NCELL ints
    int*   fill   = (int*)(ws + 4096);              // NCELL ints
    int*   cstart = (int*)(ws + 8192);              // NCELL+1 ints
    int*   cellid = (int*)(ws + 16384);             // NPTS ints (512 KB)
    float* bx     = (float*)(ws + 16384 + (size_t)NPTS*4);
    float* by     = bx + NPTS;
    float* bz     = by + NPTS;

    k_zero   <<<1, 1024, 0, stream>>>(hist, fill);
    k_hist   <<<NPTS/256, 256, 0, stream>>>(pts, cellid, hist);
    k_scan   <<<1, 1024, 0, stream>>>(hist, cstart);
    k_scatter<<<NPTS/256, 256, 0, stream>>>(pts, cellid, cstart, fill, bx, by, bz);
    k_main   <<<NANCH, 256, 0, stream>>>(pts, anch, W1, b1, W2, b2, Wc, bc, Wr, br,
                                         bx, by, bz, cstart, out);
}